// Round 10
// baseline (1294.930 us; speedup 1.0000x reference)
//
#include <hip/hip_runtime.h>
#include <hip/hip_bf16.h>
#include <cstdint>

// Problem constants: B=64, T=512, E=256, H=128, 4H=512.
#define BB 64
#define TT 512
#define EE 256
#define HH 128
#define G4 512

typedef _Float16 half2_t __attribute__((ext_vector_type(2)));
typedef _Float16 f16x4 __attribute__((ext_vector_type(4)));
typedef _Float16 f16x8 __attribute__((ext_vector_type(8)));
typedef float f32x4 __attribute__((ext_vector_type(4)));

#define BC(x) __builtin_bit_cast(half2_t, x)

// raw barrier: LDS-visibility only, does NOT drain vmcnt (global prefetch
// loads stay in flight across it).
#define BAR() asm volatile("s_waitcnt lgkmcnt(0)\n\ts_barrier" ::: "memory")

__device__ __forceinline__ float fdot2f(half2_t a, half2_t b, float c) {
#if defined(__has_builtin)
#if __has_builtin(__builtin_amdgcn_fdot2)
  return __builtin_amdgcn_fdot2(a, b, c, false);
#else
  return c + (float)a[0] * (float)b[0] + (float)a[1] * (float)b[1];
#endif
#else
  return c + (float)a[0] * (float)b[0] + (float)a[1] * (float)b[1];
#endif
}

__device__ __forceinline__ float rcp_(float x) { return __builtin_amdgcn_rcpf(x); }
__device__ __forceinline__ float tanh_(float x) {
  float ax = fabsf(x);
  float e = __expf(-2.f * ax);             // in (0,1], no overflow ever
  float r = (1.f - e) * rcp_(1.f + e);
  return copysignf(r, x);
}

__device__ __forceinline__ float readlane_f(float x, int lane) {
#if defined(__has_builtin)
#if __has_builtin(__builtin_amdgcn_readlane)
  return __builtin_bit_cast(float, __builtin_amdgcn_readlane(__builtin_bit_cast(int, x), lane));
#else
  return __shfl(x, lane);
#endif
#else
  return __shfl(x, lane);
#endif
}

#if defined(__has_builtin)
#if __has_builtin(__builtin_amdgcn_update_dpp)
#define HAVE_DPP 1
#endif
#endif

// VALU-pipe cross-lane move: dst lane n <- src lane n+N within 16-lane rows.
// (row_shr:k = lane n <- n-k is verified by the passing wave_sum; shl is the
// mirror.)  ctrl: row_shl:N = 0x100|N.
#ifdef HAVE_DPP
#define DPP_SHL(dst, src, N)                                                   \
  dst = __builtin_bit_cast(float, __builtin_amdgcn_update_dpp(                 \
            0, __builtin_bit_cast(int, src), 0x100 | (N), 0xf, 0xf, true))
#else
#define DPP_SHL(dst, src, N) dst = __shfl((src), (threadIdx.x & 63) + (N))
#endif

__device__ __forceinline__ float wave_sum64_bcast(float x) {
#ifdef HAVE_DPP
#define DPP_ADD(ctrl)                                                          \
  {                                                                            \
    int _t = __builtin_amdgcn_update_dpp(0, __builtin_bit_cast(int, x), ctrl,  \
                                         0xf, 0xf, true);                      \
    x += __builtin_bit_cast(float, _t);                                        \
  }
  DPP_ADD(0x111)  // row_shr:1
  DPP_ADD(0x112)  // row_shr:2
  DPP_ADD(0x114)  // row_shr:4
  DPP_ADD(0x118)  // row_shr:8
  DPP_ADD(0x142)  // row_bcast:15
  DPP_ADD(0x143)  // row_bcast:31
#undef DPP_ADD
  return readlane_f(x, 63);
#else
#pragma unroll
  for (int s = 1; s <= 32; s <<= 1) x += __shfl_xor(x, s);
  return x;
#endif
}

// unit-major permutation of the 4H gate-row index: j (= g*128+u) -> 4u+g
__device__ __host__ __forceinline__ int permj(int j) {
  return ((j & 127) << 2) | (j >> 7);
}

// ---------------------------------------------------------------------------
// Kernel A: trans = row-softmax(transition); W16 = (f16)W_ih with rows
// permuted to unit-major order (row' = 4u+g).
// ---------------------------------------------------------------------------
__global__ __launch_bounds__(128) void prep_kernel(
    const float* __restrict__ transition, const float* __restrict__ W_ih,
    float* __restrict__ trans, _Float16* __restrict__ W16) {
  const int bid = blockIdx.x, t = threadIdx.x;
  if (bid < 128) {
    __shared__ float red[2];
    float v = transition[bid * HH + t];
    float m = v;
#pragma unroll
    for (int s = 32; s >= 1; s >>= 1) m = fmaxf(m, __shfl_xor(m, s));
    if ((t & 63) == 0) red[t >> 6] = m;
    __syncthreads();
    m = fmaxf(red[0], red[1]);
    float e = __expf(v - m);
    float s = e;
#pragma unroll
    for (int k = 32; k >= 1; k >>= 1) s += __shfl_xor(s, k);
    __syncthreads();  // protect red before reuse
    if ((t & 63) == 0) red[t >> 6] = s;
    __syncthreads();
    trans[bid * HH + t] = e * rcp_(red[0] + red[1]);
  } else {
    const int base = (bid - 128) * 1024 + t * 8;  // 131072 total elems
    const int row = base >> 8;
    const int col = base & 255;
    float4 v0 = *(const float4*)(W_ih + base);
    float4 v1 = *(const float4*)(W_ih + base + 4);
    f16x8 h;
    h[0] = (_Float16)v0.x; h[1] = (_Float16)v0.y;
    h[2] = (_Float16)v0.z; h[3] = (_Float16)v0.w;
    h[4] = (_Float16)v1.x; h[5] = (_Float16)v1.y;
    h[6] = (_Float16)v1.z; h[7] = (_Float16)v1.w;
    *(f16x8*)(W16 + (size_t)permj(row) * EE + col) = h;
  }
}

// ---------------------------------------------------------------------------
// Kernel B: precomp[m][j'] = sum_e inputs[m][e]*W_ih[orig(j')][e] + bias.
// ---------------------------------------------------------------------------
__global__ __launch_bounds__(256) void gemm_in(
    const float* __restrict__ A, const _Float16* __restrict__ W16,
    const float* __restrict__ b_ih, const float* __restrict__ b_hh,
    float* __restrict__ out) {
  __shared__ _Float16 As[64][264];  // K=256 + 8 pad
  const int t = threadIdx.x;
  const int m0 = blockIdx.x * 64;
  const int n0 = blockIdx.y * 256;
  {
    const int c4 = t & 63, r0 = t >> 6;
#pragma unroll
    for (int p = 0; p < 16; ++p) {
      const int row = r0 + 4 * p;
      float4 v = *(const float4*)(A + (size_t)(m0 + row) * EE + c4 * 4);
      f16x4 h;
      h[0] = (_Float16)v.x; h[1] = (_Float16)v.y;
      h[2] = (_Float16)v.z; h[3] = (_Float16)v.w;
      *(f16x4*)&As[row][c4 * 4] = h;
    }
  }
  __syncthreads();
  const int w = t >> 6, L = t & 63;
  const int lrow = L & 15, quad = L >> 4, lk = quad * 8;
  f32x4 acc[4][4] = {};
  const _Float16* Wbase = W16 + (size_t)(n0 + w * 64) * EE;
#pragma unroll
  for (int kc = 0; kc < 8; ++kc) {
    f16x8 a[4], bf[4];
#pragma unroll
    for (int mf = 0; mf < 4; ++mf)
      a[mf] = *(const f16x8*)&As[mf * 16 + lrow][kc * 32 + lk];
#pragma unroll
    for (int nf = 0; nf < 4; ++nf)
      bf[nf] = *(const f16x8*)(Wbase + (size_t)(nf * 16 + lrow) * EE + kc * 32 + lk);
#pragma unroll
    for (int mf = 0; mf < 4; ++mf)
#pragma unroll
      for (int nf = 0; nf < 4; ++nf)
        acc[mf][nf] = __builtin_amdgcn_mfma_f32_16x16x32_f16(a[mf], bf[nf], acc[mf][nf], 0, 0, 0);
  }
#pragma unroll
  for (int nf = 0; nf < 4; ++nf) {
    const int j = n0 + w * 64 + nf * 16 + lrow;        // permuted col
    const int jo = ((j & 3) << 7) | (j >> 2);          // original gate index
    const float bias = b_ih[jo] + b_hh[jo];
#pragma unroll
    for (int mf = 0; mf < 4; ++mf) {
#pragma unroll
      for (int r = 0; r < 4; ++r) {
        const int m = m0 + mf * 16 + quad * 4 + r;
        out[(size_t)m * G4 + j] = acc[mf][nf][r] + bias;
      }
    }
  }
}

// ---------------------------------------------------------------------------
// Kernel C: fused LSTM + softmax + CRF, WAVE-SPECIALIZED, 1 barrier/step.
// 640 threads: waves 0-7 = LSTM (R9's verified MFMA matvec), waves 8-9 = CRF.
// Pipeline: in phase P(s), LSTM computes h(s+1) from h(s) while CRF waves
// finalize step s-1 (softmax p(s-1) from h(s-1)=ring[s&3]; S(s-1) from
// E(s-2)).  The two chains share nothing intra-phase -> they overlap instead
// of serializing (the R0-R9 skeleton summed them; ~2060 cy/step invariant).
//   * cell update IN-WAVE: gates of unit 16w+4tf+q live in lanes l15 =
//     tf,tf+4,tf+8,tf+12 (R9 C-layout) -> 3 DPP row_shl moves (VALU pipe);
//     act[]/Spart[] LDS arrays and the phase-3 tail are deleted.
//   * CRF: 1 column/lane (2 waves x 64); et column in 64 VGPRs; full S-dot
//     = 64 fdot2; per-wave softmax denom via DPP (each wave reads all h).
//     Two waves' E-normalizers reconciled cross-phase:
//     lgS = C + log(e^(Mlo-C)*Slo + e^(Mhi-C)*Shi)  (exact).
//   * h kept in f32 side-ring for softmax (same numerics as R9 phase 3).
// ---------------------------------------------------------------------------
__global__ __launch_bounds__(640, 1) void lstm_crf(
    const float* __restrict__ precomp, const float* __restrict__ Whh,
    const float* __restrict__ trans, const int* __restrict__ labels,
    float* __restrict__ out_b) {
  const int b = blockIdx.x, t = threadIdx.x;
  const int w = t >> 6, l = t & 63, q = l >> 4, l15 = l & 15;
  const int tf_a = l15 & 3;        // tile this lane activates (LSTM)
  const int gg = l15 >> 2;         // gate this lane activates (LSTM)
  const bool isL = (w < 8);
  const int cw = w - 8;            // CRF wave index (0/1) when !isL
  const int j = cw * 64 + l;       // CRF column

  __shared__ __align__(16) _Float16 h16[4][HH];  // ring: matvec operand
  __shared__ __align__(16) float h32[4][HH];     // ring: softmax operand
  __shared__ __align__(16) _Float16 E16[2][HH];
  __shared__ float Mld[2][2];
  __shared__ float fin[8];
  __shared__ int lab[TT];

  // --- per-role one-time loads ---------------------------------------------
  f16x8 wfr[4][4];                 // LSTM: W_hh A-fragments
  f32x4 pc_cur[4], pc_nxt[4];      // LSTM: precomp prefetch
  const float* pcb = nullptr;
  float c = 0.f;                   // LSTM: cell state (gg==0 lanes)
  half2_t et[64];                  // CRF: exp(trans[i][j]) pairs over i
  float tr0 = 0.f, tr127 = 0.f, pre = 0.f, emit = 0.f;

  if (isL) {
#pragma unroll
    for (int tf = 0; tf < 4; ++tf) {
      const int rowp = 16 * (4 * w + tf) + l15;   // unit-major row index
      const int u = rowp >> 2, g = rowp & 3;
      const float* src = Whh + (size_t)(g * HH + u) * HH;
#pragma unroll
      for (int kt = 0; kt < 4; ++kt) {
        const float* s8 = src + kt * 32 + q * 8;
        float4 v0 = *(const float4*)s8;
        float4 v1 = *(const float4*)(s8 + 4);
        f16x8 h8;
        h8[0] = (_Float16)v0.x; h8[1] = (_Float16)v0.y;
        h8[2] = (_Float16)v0.z; h8[3] = (_Float16)v0.w;
        h8[4] = (_Float16)v1.x; h8[5] = (_Float16)v1.y;
        h8[6] = (_Float16)v1.z; h8[7] = (_Float16)v1.w;
        wfr[tf][kt] = h8;
      }
    }
    pcb = precomp + (size_t)b * TT * G4 + 64 * w + 4 * q;
#pragma unroll
    for (int tf = 0; tf < 4; ++tf) pc_cur[tf] = *(const f32x4*)(pcb + 16 * tf);
  } else {
#pragma unroll
    for (int i = 0; i < 64; ++i) {
      float e0 = __expf(trans[(2 * i) * HH + j]);
      float e1 = __expf(trans[(2 * i + 1) * HH + j]);
      half2_t h2; h2[0] = (_Float16)e0; h2[1] = (_Float16)e1;
      et[i] = h2;
    }
    tr0 = trans[j];
    tr127 = trans[127 * HH + j];
  }
  if (t < TT) lab[t] = labels[b * TT + t];
  if (t < HH) { h16[0][t] = (_Float16)0.f; h32[0][t] = 0.f; }
  __syncthreads();

#pragma unroll 1
  for (int s = 0; s <= TT; ++s) {
    if (isL) {
      if (s < TT) {
        const int sn = (s < TT - 1) ? s + 1 : s;
#pragma unroll
        for (int tf = 0; tf < 4; ++tf)
          pc_nxt[tf] = *(const f32x4*)(pcb + (size_t)sn * G4 + 16 * tf);
        const int rs = s & 3;
        const f16x8 hb0 = *(const f16x8*)&h16[rs][q * 8];
        const f16x8 hb1 = *(const f16x8*)&h16[rs][32 + q * 8];
        const f16x8 hb2 = *(const f16x8*)&h16[rs][64 + q * 8];
        const f16x8 hb3 = *(const f16x8*)&h16[rs][96 + q * 8];
        f32x4 a0 = pc_cur[0], a1 = pc_cur[1], a2 = pc_cur[2], a3 = pc_cur[3];
        a0 = __builtin_amdgcn_mfma_f32_16x16x32_f16(wfr[0][0], hb0, a0, 0, 0, 0);
        a1 = __builtin_amdgcn_mfma_f32_16x16x32_f16(wfr[1][0], hb0, a1, 0, 0, 0);
        a2 = __builtin_amdgcn_mfma_f32_16x16x32_f16(wfr[2][0], hb0, a2, 0, 0, 0);
        a3 = __builtin_amdgcn_mfma_f32_16x16x32_f16(wfr[3][0], hb0, a3, 0, 0, 0);
        a0 = __builtin_amdgcn_mfma_f32_16x16x32_f16(wfr[0][1], hb1, a0, 0, 0, 0);
        a1 = __builtin_amdgcn_mfma_f32_16x16x32_f16(wfr[1][1], hb1, a1, 0, 0, 0);
        a2 = __builtin_amdgcn_mfma_f32_16x16x32_f16(wfr[2][1], hb1, a2, 0, 0, 0);
        a3 = __builtin_amdgcn_mfma_f32_16x16x32_f16(wfr[3][1], hb1, a3, 0, 0, 0);
        a0 = __builtin_amdgcn_mfma_f32_16x16x32_f16(wfr[0][2], hb2, a0, 0, 0, 0);
        a1 = __builtin_amdgcn_mfma_f32_16x16x32_f16(wfr[1][2], hb2, a1, 0, 0, 0);
        a2 = __builtin_amdgcn_mfma_f32_16x16x32_f16(wfr[2][2], hb2, a2, 0, 0, 0);
        a3 = __builtin_amdgcn_mfma_f32_16x16x32_f16(wfr[3][2], hb2, a3, 0, 0, 0);
        a0 = __builtin_amdgcn_mfma_f32_16x16x32_f16(wfr[0][3], hb3, a0, 0, 0, 0);
        a1 = __builtin_amdgcn_mfma_f32_16x16x32_f16(wfr[1][3], hb3, a1, 0, 0, 0);
        a2 = __builtin_amdgcn_mfma_f32_16x16x32_f16(wfr[2][3], hb3, a2, 0, 0, 0);
        a3 = __builtin_amdgcn_mfma_f32_16x16x32_f16(wfr[3][3], hb3, a3, 0, 0, 0);
        // one activation per lane: gate gg of tile tf_a (R9-verified layout)
        const f32x4 asel = (tf_a == 0) ? a0 : (tf_a == 1) ? a1 : (tf_a == 2) ? a2 : a3;
        const float gv = (gg == 0) ? asel[0] : (gg == 1) ? asel[1]
                       : (gg == 2) ? asel[2] : asel[3];
        const bool isg = (gg == 2);               // gate 2 = g -> tanh
        const float yy = isg ? (-2.f * fabsf(gv)) : (-gv);
        const float exv = __expf(yy);
        const float num = isg ? (1.f - exv) : 1.f;
        float av = num * rcp_(1.f + exv);
        av = isg ? copysignf(av, gv) : av;
        // in-wave gather: gates of unit 16w+4tf+q sit at l15 = tf+4*gate
        float Fv, Gv, Ov;
        DPP_SHL(Fv, av, 4);   // gate 1 (f)
        DPP_SHL(Gv, av, 8);   // gate 2 (g, tanh'd)
        DPP_SHL(Ov, av, 12);  // gate 3 (o)
        c = Fv * c + av * Gv;               // valid on gg==0 lanes
        const float hv = Ov * tanh_(c);
        if (gg == 0) {
          const int ua = 16 * w + 4 * l15 + q;  // l15 == tf here
          h16[(s + 1) & 3][ua] = (_Float16)hv;
          h32[(s + 1) & 3][ua] = hv;
        }
#pragma unroll
        for (int tf = 0; tf < 4; ++tf) pc_cur[tf] = pc_nxt[tf];
      }
    } else if (s >= 1) {
      // --- CRF finalize step s-1 (h written in P(s-1) -> ring slot s&3) ----
      const int rs = s & 3;
      const float2 hp = *(const float2*)&h32[rs][2 * l];
      const float denom = wave_sum64_bcast(__expf(hp.x) + __expf(hp.y));
      const float hj = h32[rs][j];
      const float p = __expf(hj) * rcp_(denom);
      if (s == 1) {
        pre = p + tr0;
      } else {
        const int rp = (s & 1) ^ 1;   // E/M written last phase
        float Slo = 0.f, Shi = 0.f;
#pragma unroll
        for (int ec = 0; ec < 8; ++ec) {
          const float4 eb = *(const float4*)&E16[rp][ec * 8];
          Slo = fdot2f(et[4 * ec + 0], BC(eb.x), Slo);
          Slo = fdot2f(et[4 * ec + 1], BC(eb.y), Slo);
          Slo = fdot2f(et[4 * ec + 2], BC(eb.z), Slo);
          Slo = fdot2f(et[4 * ec + 3], BC(eb.w), Slo);
        }
#pragma unroll
        for (int ec = 8; ec < 16; ++ec) {
          const float4 eb = *(const float4*)&E16[rp][ec * 8];
          Shi = fdot2f(et[4 * ec + 0], BC(eb.x), Shi);
          Shi = fdot2f(et[4 * ec + 1], BC(eb.y), Shi);
          Shi = fdot2f(et[4 * ec + 2], BC(eb.z), Shi);
          Shi = fdot2f(et[4 * ec + 3], BC(eb.w), Shi);
        }
        const float Mlo = Mld[rp][0], Mhi = Mld[rp][1];
        const float Cc = fmaxf(Mlo, Mhi);
        const float lgS = Cc + __logf(__expf(Mlo - Cc) * Slo + __expf(Mhi - Cc) * Shi);
        pre = p + lgS;
      }
      if (j == lab[s - 1]) emit += p;
      const float Mw = readlane_f(pre, 0);           // per-wave normalizer
      E16[s & 1][j] = (_Float16)__expf(pre - Mw);    // ~exp(±0.1): f16-safe
      if (l == 0) Mld[s & 1][cw] = Mw;
    }
    BAR();
  }
  // --- epilogue: Ps = LSE_j(pre + trans[127][j]); out_b = Ps - emit --------
  if (!isL) {
    float v = pre + tr127;
    float m = v;
#pragma unroll
    for (int s2 = 1; s2 <= 32; s2 <<= 1) m = fmaxf(m, __shfl_xor(m, s2));
    if (l == 0) fin[cw] = m;
  }
  __syncthreads();
  if (!isL) {
    const float M2 = fmaxf(fin[0], fin[1]);
    float ex = __expf(pre + tr127 - M2);
    float em = emit;
#pragma unroll
    for (int s2 = 1; s2 <= 32; s2 <<= 1) {
      ex += __shfl_xor(ex, s2);
      em += __shfl_xor(em, s2);
    }
    if (l == 0) { fin[2 + cw] = ex; fin[4 + cw] = em; }
  }
  __syncthreads();
  if (t == 0)
    out_b[b] = fmaxf(fin[0], fin[1]) + __logf(fin[2] + fin[3]) - (fin[4] + fin[5]);
}

// ---------------------------------------------------------------------------
// Kernel D: total = sum_b out_b[b] - sum_{b,t<511} trans[l_t][l_{t+1}]
// ---------------------------------------------------------------------------
__global__ __launch_bounds__(512) void finalize_kernel(
    const float* __restrict__ trans, const int* __restrict__ labels,
    const float* __restrict__ out_b, float* __restrict__ d_out) {
  const int t = threadIdx.x;
  float a = 0.f;
  if (t < TT - 1) {
    for (int b = 0; b < BB; ++b) {
      const int l0 = labels[b * TT + t];
      const int l1 = labels[b * TT + t + 1];
      a += trans[l0 * HH + l1];
    }
  }
  float x = ((t < BB) ? out_b[t] : 0.f) - a;
  __shared__ float red[8];
#pragma unroll
  for (int s = 32; s >= 1; s >>= 1) x += __shfl_xor(x, s);
  if ((t & 63) == 0) red[t >> 6] = x;
  __syncthreads();
  if (t == 0) {
    float s = 0.f;
#pragma unroll
    for (int i = 0; i < 8; ++i) s += red[i];
    d_out[0] = s;
  }
}

// ---------------------------------------------------------------------------
extern "C" void kernel_launch(void* const* d_in, const int* in_sizes, int n_in,
                              void* d_out, int out_size, void* d_ws, size_t ws_size,
                              hipStream_t stream) {
  const float* inputs = (const float*)d_in[0];      // (64,512,256) f32
  const int* labels = (const int*)d_in[1];          // (64,512) i32
  const float* W_ih = (const float*)d_in[2];        // (512,256) f32
  const float* W_hh = (const float*)d_in[3];        // (512,128) f32
  const float* b_ih = (const float*)d_in[4];        // (512,) f32
  const float* b_hh = (const float*)d_in[5];        // (512,) f32
  const float* transition = (const float*)d_in[6];  // (128,128) f32

  char* ws = (char*)d_ws;
  float* precomp = (float*)ws;                           // 64 MiB
  float* trans = (float*)(ws + 67108864);                // 64 KiB
  _Float16* W16 = (_Float16*)(ws + 67108864 + 65536);    // 256 KiB
  float* out_b = (float*)(ws + 67108864 + 65536 + 262144);

  prep_kernel<<<256, 128, 0, stream>>>(transition, W_ih, trans, W16);
  gemm_in<<<dim3(512, 2), 256, 0, stream>>>(inputs, W16, b_ih, b_hh, precomp);
  lstm_crf<<<64, 640, 0, stream>>>(precomp, W_hh, trans, labels, out_b);
  finalize_kernel<<<1, 512, 0, stream>>>(trans, labels, out_b, (float*)d_out);
}

// Round 11
// 615.417 us; speedup vs baseline: 2.1042x; 2.1042x over previous
//
#include <hip/hip_runtime.h>
#include <hip/hip_bf16.h>
#include <cstdint>

// Problem constants: B=64, T=512, E=256, H=128, 4H=512.
#define BB 64
#define TT 512
#define EE 256
#define HH 128
#define G4 512

typedef _Float16 half2_t __attribute__((ext_vector_type(2)));
typedef _Float16 f16x4 __attribute__((ext_vector_type(4)));
typedef _Float16 f16x8 __attribute__((ext_vector_type(8)));
typedef float f32x4 __attribute__((ext_vector_type(4)));

#define BC(x) __builtin_bit_cast(half2_t, x)

// raw barrier: LDS-visibility only, does NOT drain vmcnt (global prefetch
// loads stay in flight across it).
#define BAR() asm volatile("s_waitcnt lgkmcnt(0)\n\ts_barrier" ::: "memory")

__device__ __forceinline__ float fdot2f(half2_t a, half2_t b, float c) {
#if defined(__has_builtin)
#if __has_builtin(__builtin_amdgcn_fdot2)
  return __builtin_amdgcn_fdot2(a, b, c, false);
#else
  return c + (float)a[0] * (float)b[0] + (float)a[1] * (float)b[1];
#endif
#else
  return c + (float)a[0] * (float)b[0] + (float)a[1] * (float)b[1];
#endif
}

__device__ __forceinline__ float rcp_(float x) { return __builtin_amdgcn_rcpf(x); }
__device__ __forceinline__ float tanh_(float x) {
  float ax = fabsf(x);
  float e = __expf(-2.f * ax);             // in (0,1], no overflow ever
  float r = (1.f - e) * rcp_(1.f + e);
  return copysignf(r, x);
}

__device__ __forceinline__ float readlane_f(float x, int lane) {
#if defined(__has_builtin)
#if __has_builtin(__builtin_amdgcn_readlane)
  return __builtin_bit_cast(float, __builtin_amdgcn_readlane(__builtin_bit_cast(int, x), lane));
#else
  return __shfl(x, lane);
#endif
#else
  return __shfl(x, lane);
#endif
}

#if defined(__has_builtin)
#if __has_builtin(__builtin_amdgcn_update_dpp)
#define HAVE_DPP 1
#endif
#endif

// VALU-pipe cross-lane move: dst lane n <- src lane n+N within 16-lane rows
// (bound_ctrl=true -> 0 when shifted out of the row).  Verified in R10.
#ifdef HAVE_DPP
#define DPP_SHL(dst, src, N)                                                   \
  dst = __builtin_bit_cast(float, __builtin_amdgcn_update_dpp(                 \
            0, __builtin_bit_cast(int, src), 0x100 | (N), 0xf, 0xf, true))
#else
#define DPP_SHL(dst, src, N) dst = __shfl((src), (threadIdx.x & 63) + (N))
#endif

__device__ __forceinline__ float wave_sum64_bcast(float x) {
#ifdef HAVE_DPP
#define DPP_ADD(ctrl)                                                          \
  {                                                                            \
    int _t = __builtin_amdgcn_update_dpp(0, __builtin_bit_cast(int, x), ctrl,  \
                                         0xf, 0xf, true);                      \
    x += __builtin_bit_cast(float, _t);                                        \
  }
  DPP_ADD(0x111)  // row_shr:1
  DPP_ADD(0x112)  // row_shr:2
  DPP_ADD(0x114)  // row_shr:4
  DPP_ADD(0x118)  // row_shr:8
  DPP_ADD(0x142)  // row_bcast:15
  DPP_ADD(0x143)  // row_bcast:31
#undef DPP_ADD
  return readlane_f(x, 63);
#else
#pragma unroll
  for (int s = 1; s <= 32; s <<= 1) x += __shfl_xor(x, s);
  return x;
#endif
}

// unit-major permutation of the 4H gate-row index: j (= g*128+u) -> 4u+g
__device__ __host__ __forceinline__ int permj(int j) {
  return ((j & 127) << 2) | (j >> 7);
}

// ---------------------------------------------------------------------------
// Kernel A: trans = row-softmax(transition); W16 = (f16)W_ih with rows
// permuted to unit-major order (row' = 4u+g).
// ---------------------------------------------------------------------------
__global__ __launch_bounds__(128) void prep_kernel(
    const float* __restrict__ transition, const float* __restrict__ W_ih,
    float* __restrict__ trans, _Float16* __restrict__ W16) {
  const int bid = blockIdx.x, t = threadIdx.x;
  if (bid < 128) {
    __shared__ float red[2];
    float v = transition[bid * HH + t];
    float m = v;
#pragma unroll
    for (int s = 32; s >= 1; s >>= 1) m = fmaxf(m, __shfl_xor(m, s));
    if ((t & 63) == 0) red[t >> 6] = m;
    __syncthreads();
    m = fmaxf(red[0], red[1]);
    float e = __expf(v - m);
    float s = e;
#pragma unroll
    for (int k = 32; k >= 1; k >>= 1) s += __shfl_xor(s, k);
    __syncthreads();  // protect red before reuse
    if ((t & 63) == 0) red[t >> 6] = s;
    __syncthreads();
    trans[bid * HH + t] = e * rcp_(red[0] + red[1]);
  } else {
    const int base = (bid - 128) * 1024 + t * 8;  // 131072 total elems
    const int row = base >> 8;
    const int col = base & 255;
    float4 v0 = *(const float4*)(W_ih + base);
    float4 v1 = *(const float4*)(W_ih + base + 4);
    f16x8 h;
    h[0] = (_Float16)v0.x; h[1] = (_Float16)v0.y;
    h[2] = (_Float16)v0.z; h[3] = (_Float16)v0.w;
    h[4] = (_Float16)v1.x; h[5] = (_Float16)v1.y;
    h[6] = (_Float16)v1.z; h[7] = (_Float16)v1.w;
    *(f16x8*)(W16 + (size_t)permj(row) * EE + col) = h;
  }
}

// ---------------------------------------------------------------------------
// Kernel B: precomp[m][j'] = sum_e inputs[m][e]*W_ih[orig(j')][e] + bias.
// ---------------------------------------------------------------------------
__global__ __launch_bounds__(256) void gemm_in(
    const float* __restrict__ A, const _Float16* __restrict__ W16,
    const float* __restrict__ b_ih, const float* __restrict__ b_hh,
    float* __restrict__ out) {
  __shared__ _Float16 As[64][264];  // K=256 + 8 pad
  const int t = threadIdx.x;
  const int m0 = blockIdx.x * 64;
  const int n0 = blockIdx.y * 256;
  {
    const int c4 = t & 63, r0 = t >> 6;
#pragma unroll
    for (int p = 0; p < 16; ++p) {
      const int row = r0 + 4 * p;
      float4 v = *(const float4*)(A + (size_t)(m0 + row) * EE + c4 * 4);
      f16x4 h;
      h[0] = (_Float16)v.x; h[1] = (_Float16)v.y;
      h[2] = (_Float16)v.z; h[3] = (_Float16)v.w;
      *(f16x4*)&As[row][c4 * 4] = h;
    }
  }
  __syncthreads();
  const int w = t >> 6, L = t & 63;
  const int lrow = L & 15, quad = L >> 4, lk = quad * 8;
  f32x4 acc[4][4] = {};
  const _Float16* Wbase = W16 + (size_t)(n0 + w * 64) * EE;
#pragma unroll
  for (int kc = 0; kc < 8; ++kc) {
    f16x8 a[4], bf[4];
#pragma unroll
    for (int mf = 0; mf < 4; ++mf)
      a[mf] = *(const f16x8*)&As[mf * 16 + lrow][kc * 32 + lk];
#pragma unroll
    for (int nf = 0; nf < 4; ++nf)
      bf[nf] = *(const f16x8*)(Wbase + (size_t)(nf * 16 + lrow) * EE + kc * 32 + lk);
#pragma unroll
    for (int mf = 0; mf < 4; ++mf)
#pragma unroll
      for (int nf = 0; nf < 4; ++nf)
        acc[mf][nf] = __builtin_amdgcn_mfma_f32_16x16x32_f16(a[mf], bf[nf], acc[mf][nf], 0, 0, 0);
  }
#pragma unroll
  for (int nf = 0; nf < 4; ++nf) {
    const int j = n0 + w * 64 + nf * 16 + lrow;        // permuted col
    const int jo = ((j & 3) << 7) | (j >> 2);          // original gate index
    const float bias = b_ih[jo] + b_hh[jo];
#pragma unroll
    for (int mf = 0; mf < 4; ++mf) {
#pragma unroll
      for (int r = 0; r < 4; ++r) {
        const int m = m0 + mf * 16 + quad * 4 + r;
        out[(size_t)m * G4 + j] = acc[mf][nf][r] + bias;
      }
    }
  }
}

// ---------------------------------------------------------------------------
// Kernel C: fused LSTM + softmax + CRF.  One 512-thread block per batch.
// = R9 (verified, 439us) with the phase-3 serial tail gutted:
//   * cell update IN PHASE 1 via DPP row_shl gather (verified in R10):
//     lane (tf_a,gg) computes its one activation; lanes gg==0 gather f,g,o
//     with 3 VALU-pipe moves, update c, write h16[pr^1] + e32[pr^1]=exp(h).
//     act[] LDS array deleted (kills R9's 1.57M bank conflicts).
//   * per-wave softmax denominator partials in phase 1 (masked DPP sum over
//     the wave's 16 units) -> ws[w].
//   * phase 3 (wave 0) = pure CRF chain: denom from ws, p from e32, Spart
//     reads, logs, max-proxy recursion, E16 write.  No tanh/exp-of-h/
//     wave-sum/h-write left on the serial tail (~500 -> ~250 cy).
// MFMA matvec, CRF quarter-dot, quantization, epilogue verbatim R9.
// ---------------------------------------------------------------------------
__global__ __launch_bounds__(512, 1) void lstm_crf(
    const float* __restrict__ precomp, const float* __restrict__ Whh,
    const float* __restrict__ trans, const int* __restrict__ labels,
    float* __restrict__ out_b) {
  const int b = blockIdx.x, t = threadIdx.x;
  const int w = t >> 6, l = t & 63, q = l >> 4, l15 = l & 15;
  const int tf_a = l15 & 3;        // tile this lane activates
  const int gg = l15 >> 2;         // gate this lane activates
  const int g2 = t >> 7, jj = t & 127;   // CRF roles (quarter, unit)

  __shared__ __align__(16) _Float16 h16[2][HH];
  __shared__ __align__(16) float e32[2][HH];
  __shared__ __align__(16) _Float16 E_lds[HH];
  __shared__ __align__(16) float Spart[G4];   // [quarter*128 + unit]
  __shared__ __align__(16) float ws[8];       // per-wave exp-sum partials
  __shared__ int lab[TT];

  // --- one-time: W_hh A-fragments (rows' = 16(4w+tf) + l15) ----------------
  f16x8 wfr[4][4];
#pragma unroll
  for (int tf = 0; tf < 4; ++tf) {
    const int rowp = 16 * (4 * w + tf) + l15;   // unit-major row index
    const int u = rowp >> 2, g = rowp & 3;
    const float* src = Whh + (size_t)(g * HH + u) * HH;
#pragma unroll
    for (int kt = 0; kt < 4; ++kt) {
      const float* s8 = src + kt * 32 + q * 8;
      float4 v0 = *(const float4*)s8;
      float4 v1 = *(const float4*)(s8 + 4);
      f16x8 h8;
      h8[0] = (_Float16)v0.x; h8[1] = (_Float16)v0.y;
      h8[2] = (_Float16)v0.z; h8[3] = (_Float16)v0.w;
      h8[4] = (_Float16)v1.x; h8[5] = (_Float16)v1.y;
      h8[6] = (_Float16)v1.z; h8[7] = (_Float16)v1.w;
      wfr[tf][kt] = h8;
    }
  }
  // et[a] = exp(trans[g2*32+2a][jj]), exp(trans[g2*32+2a+1][jj])
  half2_t et[16];
#pragma unroll
  for (int a = 0; a < 16; ++a) {
    float e0 = __expf(trans[(g2 * 32 + 2 * a) * HH + jj]);
    float e1 = __expf(trans[(g2 * 32 + 2 * a + 1) * HH + jj]);
    half2_t h2; h2[0] = (_Float16)e0; h2[1] = (_Float16)e1;
    et[a] = h2;
  }
  lab[t] = labels[b * TT + t];
  if (t < HH) { h16[0][t] = (_Float16)0.f; E_lds[t] = (_Float16)0.f; }

  // wave-0 persistent CRF state (units 2t, 2t+1)
  float tr0x = 0.f, tr0y = 0.f, tr127x = 0.f, tr127y = 0.f;
  if (t < 64) {
    float2 v0 = *(const float2*)(trans + 2 * t);
    float2 v1 = *(const float2*)(trans + 127 * HH + 2 * t);
    tr0x = v0.x; tr0y = v0.y; tr127x = v1.x; tr127y = v1.y;
  }
  float c = 0.f;   // cell state (valid on gg==0 lanes)
  float preA = 0.f, preB = 0.f, mused = 0.f, emit = 0.f;

  // precomp (unit-major cols): lane needs rows' 64w+16tf+4q..+3 per tile
  const float* pcb = precomp + (size_t)b * TT * G4 + 64 * w + 4 * q;
  f32x4 pc_cur[4], pc_nxt[4];
#pragma unroll
  for (int tf = 0; tf < 4; ++tf) pc_cur[tf] = *(const f32x4*)(pcb + 16 * tf);
  __syncthreads();

#pragma unroll 1
  for (int step = 0; step < TT; ++step) {
    const int pr = step & 1;
    const int sn = (step < TT - 1) ? step + 1 : step;
#pragma unroll
    for (int tf = 0; tf < 4; ++tf)
      pc_nxt[tf] = *(const f32x4*)(pcb + (size_t)sn * G4 + 16 * tf);
    // --- B-fragments of h (4 reads cover all of h for the whole wave) ------
    const f16x8 hb0 = *(const f16x8*)&h16[pr][q * 8];
    const f16x8 hb1 = *(const f16x8*)&h16[pr][32 + q * 8];
    const f16x8 hb2 = *(const f16x8*)&h16[pr][64 + q * 8];
    const f16x8 hb3 = *(const f16x8*)&h16[pr][96 + q * 8];
    // --- gate matvec: 4 row-tiles x 4 k-tiles, acc init = precomp ----------
    f32x4 a0 = pc_cur[0], a1 = pc_cur[1], a2 = pc_cur[2], a3 = pc_cur[3];
    a0 = __builtin_amdgcn_mfma_f32_16x16x32_f16(wfr[0][0], hb0, a0, 0, 0, 0);
    a1 = __builtin_amdgcn_mfma_f32_16x16x32_f16(wfr[1][0], hb0, a1, 0, 0, 0);
    a2 = __builtin_amdgcn_mfma_f32_16x16x32_f16(wfr[2][0], hb0, a2, 0, 0, 0);
    a3 = __builtin_amdgcn_mfma_f32_16x16x32_f16(wfr[3][0], hb0, a3, 0, 0, 0);
    a0 = __builtin_amdgcn_mfma_f32_16x16x32_f16(wfr[0][1], hb1, a0, 0, 0, 0);
    a1 = __builtin_amdgcn_mfma_f32_16x16x32_f16(wfr[1][1], hb1, a1, 0, 0, 0);
    a2 = __builtin_amdgcn_mfma_f32_16x16x32_f16(wfr[2][1], hb1, a2, 0, 0, 0);
    a3 = __builtin_amdgcn_mfma_f32_16x16x32_f16(wfr[3][1], hb1, a3, 0, 0, 0);
    a0 = __builtin_amdgcn_mfma_f32_16x16x32_f16(wfr[0][2], hb2, a0, 0, 0, 0);
    a1 = __builtin_amdgcn_mfma_f32_16x16x32_f16(wfr[1][2], hb2, a1, 0, 0, 0);
    a2 = __builtin_amdgcn_mfma_f32_16x16x32_f16(wfr[2][2], hb2, a2, 0, 0, 0);
    a3 = __builtin_amdgcn_mfma_f32_16x16x32_f16(wfr[3][2], hb2, a3, 0, 0, 0);
    a0 = __builtin_amdgcn_mfma_f32_16x16x32_f16(wfr[0][3], hb3, a0, 0, 0, 0);
    a1 = __builtin_amdgcn_mfma_f32_16x16x32_f16(wfr[1][3], hb3, a1, 0, 0, 0);
    a2 = __builtin_amdgcn_mfma_f32_16x16x32_f16(wfr[2][3], hb3, a2, 0, 0, 0);
    a3 = __builtin_amdgcn_mfma_f32_16x16x32_f16(wfr[3][3], hb3, a3, 0, 0, 0);
    // --- CRF quarter dot (verbatim R4/R9) ----------------------------------
    float s0 = 0.f, s1 = 0.f;
    const float4* ev4 = (const float4*)E_lds + g2 * 4;
#pragma unroll
    for (int ec = 0; ec < 4; ++ec) {
      float4 eb = ev4[ec];
      s0 = fdot2f(et[4 * ec + 0], BC(eb.x), s0);
      s1 = fdot2f(et[4 * ec + 1], BC(eb.y), s1);
      s0 = fdot2f(et[4 * ec + 2], BC(eb.z), s0);
      s1 = fdot2f(et[4 * ec + 3], BC(eb.w), s1);
    }
    // --- ONE activation per lane + in-wave cell update (R10-verified) ------
    const f32x4 asel = (tf_a == 0) ? a0 : (tf_a == 1) ? a1 : (tf_a == 2) ? a2 : a3;
    const float gv = (gg == 0) ? asel[0] : (gg == 1) ? asel[1]
                   : (gg == 2) ? asel[2] : asel[3];
    const bool isg = (gg == 2);               // gate 2 = g -> tanh
    const float yy = isg ? (-2.f * fabsf(gv)) : (-gv);
    const float exv = __expf(yy);
    const float num = isg ? (1.f - exv) : 1.f;
    float av = num * rcp_(1.f + exv);
    av = isg ? copysignf(av, gv) : av;
    // gather f,g,o onto gg==0 lanes: gates of unit 16w+4tf+q at l15=tf+4*gate
    float Fv, Gv, Ov;
    DPP_SHL(Fv, av, 4);   // gate 1 (f)
    DPP_SHL(Gv, av, 8);   // gate 2 (g, tanh'd)
    DPP_SHL(Ov, av, 12);  // gate 3 (o)
    c = Fv * c + av * Gv;               // valid on gg==0; bounded elsewhere
    const float hv = Ov * tanh_(c);
    const float eh = __expf(hv);        // |hv|<1 on gg==0 lanes
    if (gg == 0) {
      const int ua = 16 * w + 4 * l15 + q;  // l15 == tf here
      h16[pr ^ 1][ua] = (_Float16)hv;
      e32[pr ^ 1][ua] = eh;
    }
    float ehm = (gg == 0) ? eh : 0.f;
    ehm = wave_sum64_bcast(ehm);        // partial denom over this wave's units
    if (l == 0) ws[w] = ehm;
    Spart[t] = s0 + s1;
    BAR();  // A: h16/e32/ws/Spart visible
    // --- phase 3 (wave 0): pure CRF chain ----------------------------------
    if (t < 64) {
      const float4 wsa = *(const float4*)ws;
      const float4 wsb = *(const float4*)(ws + 4);
      const float denom = ((wsa.x + wsa.y) + (wsa.z + wsa.w)) +
                          ((wsb.x + wsb.y) + (wsb.z + wsb.w));
      const float2 ep = *(const float2*)&e32[pr ^ 1][2 * t];
      const float rinv = rcp_(denom);
      const float p0 = ep.x * rinv, p1 = ep.y * rinv;
      const float2* s2p = (const float2*)Spart;
      float2 Sq0 = s2p[t], Sq1 = s2p[64 + t], Sq2 = s2p[128 + t], Sq3 = s2p[192 + t];
      const float Sa = (Sq0.x + Sq1.x) + (Sq2.x + Sq3.x);
      const float Sb = (Sq0.y + Sq1.y) + (Sq2.y + Sq3.y);
      const float lgSa = __logf(Sa), lgSb = __logf(Sb);
      const float lgS0 = readlane_f(lgSa, 0);      // unit 0's log S
      const int lb = lab[step];
      const float Mnext = (step == 0) ? 0.f : (mused + lgS0);
      preA = p0 + ((step == 0) ? tr0x : (mused + lgSa));
      preB = p1 + ((step == 0) ? tr0y : (mused + lgSb));
      if (2 * t == lb) emit += p0;
      if (2 * t + 1 == lb) emit += p1;
      half2_t Eh;
      Eh[0] = (_Float16)__expf(preA - Mnext);  // bounded ~[0.37, 7.4]
      Eh[1] = (_Float16)__expf(preB - Mnext);
      *(half2_t*)&E_lds[2 * t] = Eh;
      mused = Mnext;
    }
    BAR();  // C: E visible
#pragma unroll
    for (int tf = 0; tf < 4; ++tf) pc_cur[tf] = pc_nxt[tf];
  }
  // --- epilogue (wave 0): Ps = LSE(pre + trans[127]); out_b = Ps - emit ----
  if (t < 64) {
    float v0 = preA + tr127x, v1 = preB + tr127y;
    float m = fmaxf(v0, v1);
#pragma unroll
    for (int s = 1; s <= 32; s <<= 1) m = fmaxf(m, __shfl_xor(m, s));
    float ex = __expf(v0 - m) + __expf(v1 - m);
    float em = emit;
#pragma unroll
    for (int s = 1; s <= 32; s <<= 1) {
      ex += __shfl_xor(ex, s);
      em += __shfl_xor(em, s);
    }
    if (t == 0) out_b[b] = m + __logf(ex) - em;
  }
}

// ---------------------------------------------------------------------------
// Kernel D: total = sum_b out_b[b] - sum_{b,t<511} trans[l_t][l_{t+1}]
// ---------------------------------------------------------------------------
__global__ __launch_bounds__(512) void finalize_kernel(
    const float* __restrict__ trans, const int* __restrict__ labels,
    const float* __restrict__ out_b, float* __restrict__ d_out) {
  const int t = threadIdx.x;
  float a = 0.f;
  if (t < TT - 1) {
    for (int b = 0; b < BB; ++b) {
      const int l0 = labels[b * TT + t];
      const int l1 = labels[b * TT + t + 1];
      a += trans[l0 * HH + l1];
    }
  }
  float x = ((t < BB) ? out_b[t] : 0.f) - a;
  __shared__ float red[8];
#pragma unroll
  for (int s = 32; s >= 1; s >>= 1) x += __shfl_xor(x, s);
  if ((t & 63) == 0) red[t >> 6] = x;
  __syncthreads();
  if (t == 0) {
    float s = 0.f;
#pragma unroll
    for (int i = 0; i < 8; ++i) s += red[i];
    d_out[0] = s;
  }
}

// ---------------------------------------------------------------------------
extern "C" void kernel_launch(void* const* d_in, const int* in_sizes, int n_in,
                              void* d_out, int out_size, void* d_ws, size_t ws_size,
                              hipStream_t stream) {
  const float* inputs = (const float*)d_in[0];      // (64,512,256) f32
  const int* labels = (const int*)d_in[1];          // (64,512) i32
  const float* W_ih = (const float*)d_in[2];        // (512,256) f32
  const float* W_hh = (const float*)d_in[3];        // (512,128) f32
  const float* b_ih = (const float*)d_in[4];        // (512,) f32
  const float* b_hh = (const float*)d_in[5];        // (512,) f32
  const float* transition = (const float*)d_in[6];  // (128,128) f32

  char* ws = (char*)d_ws;
  float* precomp = (float*)ws;                           // 64 MiB
  float* trans = (float*)(ws + 67108864);                // 64 KiB
  _Float16* W16 = (_Float16*)(ws + 67108864 + 65536);    // 256 KiB
  float* out_b = (float*)(ws + 67108864 + 65536 + 262144);

  prep_kernel<<<256, 128, 0, stream>>>(transition, W_ih, trans, W16);
  gemm_in<<<dim3(512, 2), 256, 0, stream>>>(inputs, W16, b_ih, b_hh, precomp);
  lstm_crf<<<64, 512, 0, stream>>>(precomp, W_hh, trans, labels, out_b);
  finalize_kernel<<<1, 512, 0, stream>>>(trans, labels, out_b, (float*)d_out);
}

// Round 12
// 510.541 us; speedup vs baseline: 2.5364x; 1.2054x over previous
//
#include <hip/hip_runtime.h>
#include <hip/hip_bf16.h>
#include <cstdint>

// Problem constants: B=64, T=512, E=256, H=128, 4H=512.
#define BB 64
#define TT 512
#define EE 256
#define HH 128
#define G4 512

typedef _Float16 half2_t __attribute__((ext_vector_type(2)));
typedef _Float16 f16x4 __attribute__((ext_vector_type(4)));
typedef _Float16 f16x8 __attribute__((ext_vector_type(8)));
typedef float f32x4 __attribute__((ext_vector_type(4)));

#define BC(x) __builtin_bit_cast(half2_t, x)

// raw barrier: LDS-visibility only, does NOT drain vmcnt.
#define BAR() asm volatile("s_waitcnt lgkmcnt(0)\n\ts_barrier" ::: "memory")

__device__ __forceinline__ float fdot2f(half2_t a, half2_t b, float c) {
#if defined(__has_builtin)
#if __has_builtin(__builtin_amdgcn_fdot2)
  return __builtin_amdgcn_fdot2(a, b, c, false);
#else
  return c + (float)a[0] * (float)b[0] + (float)a[1] * (float)b[1];
#endif
#else
  return c + (float)a[0] * (float)b[0] + (float)a[1] * (float)b[1];
#endif
}

__device__ __forceinline__ float rcp_(float x) { return __builtin_amdgcn_rcpf(x); }
__device__ __forceinline__ float tanh_(float x) {
  float ax = fabsf(x);
  float e = __expf(-2.f * ax);             // in (0,1], no overflow ever
  float r = (1.f - e) * rcp_(1.f + e);
  return copysignf(r, x);
}

__device__ __forceinline__ float readlane_f(float x, int lane) {
#if defined(__has_builtin)
#if __has_builtin(__builtin_amdgcn_readlane)
  return __builtin_bit_cast(float, __builtin_amdgcn_readlane(__builtin_bit_cast(int, x), lane));
#else
  return __shfl(x, lane);
#endif
#else
  return __shfl(x, lane);
#endif
}

#if defined(__has_builtin)
#if __has_builtin(__builtin_amdgcn_update_dpp)
#define HAVE_DPP 1
#endif
#endif

// VALU-pipe cross-lane move: lane n <- lane n+N within 16-lane rows (R10-verified).
#ifdef HAVE_DPP
#define DPP_SHL(dst, src, N)                                                   \
  dst = __builtin_bit_cast(float, __builtin_amdgcn_update_dpp(                 \
            0, __builtin_bit_cast(int, src), 0x100 | (N), 0xf, 0xf, true))
// quad_perm [1,0,3,2]: swap lane pairs (xor 1) on the VALU pipe.
#define DPP_QSWAP(dst, src)                                                    \
  dst = __builtin_bit_cast(float, __builtin_amdgcn_update_dpp(                 \
            0, __builtin_bit_cast(int, src), 0xB1, 0xf, 0xf, true))
#else
#define DPP_SHL(dst, src, N) dst = __shfl((src), (threadIdx.x & 63) + (N))
#define DPP_QSWAP(dst, src) dst = __shfl_xor((src), 1)
#endif

__device__ __forceinline__ float wave_sum64_bcast(float x) {
#ifdef HAVE_DPP
#define DPP_ADD(ctrl)                                                          \
  {                                                                            \
    int _t = __builtin_amdgcn_update_dpp(0, __builtin_bit_cast(int, x), ctrl,  \
                                         0xf, 0xf, true);                      \
    x += __builtin_bit_cast(float, _t);                                        \
  }
  DPP_ADD(0x111)  // row_shr:1
  DPP_ADD(0x112)  // row_shr:2
  DPP_ADD(0x114)  // row_shr:4
  DPP_ADD(0x118)  // row_shr:8
  DPP_ADD(0x142)  // row_bcast:15
  DPP_ADD(0x143)  // row_bcast:31
#undef DPP_ADD
  return readlane_f(x, 63);
#else
#pragma unroll
  for (int s = 1; s <= 32; s <<= 1) x += __shfl_xor(x, s);
  return x;
#endif
}

// unit-major permutation of the 4H gate-row index: j (= g*128+u) -> 4u+g
__device__ __host__ __forceinline__ int permj(int j) {
  return ((j & 127) << 2) | (j >> 7);
}

// ---------------------------------------------------------------------------
// Kernel A: trans = row-softmax(transition); W16 = (f16)W_ih, rows permuted
// to unit-major order (row' = 4u+g).
// ---------------------------------------------------------------------------
__global__ __launch_bounds__(128) void prep_kernel(
    const float* __restrict__ transition, const float* __restrict__ W_ih,
    float* __restrict__ trans, _Float16* __restrict__ W16) {
  const int bid = blockIdx.x, t = threadIdx.x;
  if (bid < 128) {
    __shared__ float red[2];
    float v = transition[bid * HH + t];
    float m = v;
#pragma unroll
    for (int s = 32; s >= 1; s >>= 1) m = fmaxf(m, __shfl_xor(m, s));
    if ((t & 63) == 0) red[t >> 6] = m;
    __syncthreads();
    m = fmaxf(red[0], red[1]);
    float e = __expf(v - m);
    float s = e;
#pragma unroll
    for (int k = 32; k >= 1; k >>= 1) s += __shfl_xor(s, k);
    __syncthreads();  // protect red before reuse
    if ((t & 63) == 0) red[t >> 6] = s;
    __syncthreads();
    trans[bid * HH + t] = e * rcp_(red[0] + red[1]);
  } else {
    const int base = (bid - 128) * 1024 + t * 8;  // 131072 total elems
    const int row = base >> 8;
    const int col = base & 255;
    float4 v0 = *(const float4*)(W_ih + base);
    float4 v1 = *(const float4*)(W_ih + base + 4);
    f16x8 h;
    h[0] = (_Float16)v0.x; h[1] = (_Float16)v0.y;
    h[2] = (_Float16)v0.z; h[3] = (_Float16)v0.w;
    h[4] = (_Float16)v1.x; h[5] = (_Float16)v1.y;
    h[6] = (_Float16)v1.z; h[7] = (_Float16)v1.w;
    *(f16x8*)(W16 + (size_t)permj(row) * EE + col) = h;
  }
}

// ---------------------------------------------------------------------------
// Kernel B: precomp[m][j'] = sum_e inputs[m][e]*W_ih[orig(j')][e] + bias.
// ---------------------------------------------------------------------------
__global__ __launch_bounds__(256) void gemm_in(
    const float* __restrict__ A, const _Float16* __restrict__ W16,
    const float* __restrict__ b_ih, const float* __restrict__ b_hh,
    float* __restrict__ out) {
  __shared__ _Float16 As[64][264];  // K=256 + 8 pad
  const int t = threadIdx.x;
  const int m0 = blockIdx.x * 64;
  const int n0 = blockIdx.y * 256;
  {
    const int c4 = t & 63, r0 = t >> 6;
#pragma unroll
    for (int p = 0; p < 16; ++p) {
      const int row = r0 + 4 * p;
      float4 v = *(const float4*)(A + (size_t)(m0 + row) * EE + c4 * 4);
      f16x4 h;
      h[0] = (_Float16)v.x; h[1] = (_Float16)v.y;
      h[2] = (_Float16)v.z; h[3] = (_Float16)v.w;
      *(f16x4*)&As[row][c4 * 4] = h;
    }
  }
  __syncthreads();
  const int w = t >> 6, L = t & 63;
  const int lrow = L & 15, quad = L >> 4, lk = quad * 8;
  f32x4 acc[4][4] = {};
  const _Float16* Wbase = W16 + (size_t)(n0 + w * 64) * EE;
#pragma unroll
  for (int kc = 0; kc < 8; ++kc) {
    f16x8 a[4], bf[4];
#pragma unroll
    for (int mf = 0; mf < 4; ++mf)
      a[mf] = *(const f16x8*)&As[mf * 16 + lrow][kc * 32 + lk];
#pragma unroll
    for (int nf = 0; nf < 4; ++nf)
      bf[nf] = *(const f16x8*)(Wbase + (size_t)(nf * 16 + lrow) * EE + kc * 32 + lk);
#pragma unroll
    for (int mf = 0; mf < 4; ++mf)
#pragma unroll
      for (int nf = 0; nf < 4; ++nf)
        acc[mf][nf] = __builtin_amdgcn_mfma_f32_16x16x32_f16(a[mf], bf[nf], acc[mf][nf], 0, 0, 0);
  }
#pragma unroll
  for (int nf = 0; nf < 4; ++nf) {
    const int j = n0 + w * 64 + nf * 16 + lrow;        // permuted col
    const int jo = ((j & 3) << 7) | (j >> 2);          // original gate index
    const float bias = b_ih[jo] + b_hh[jo];
#pragma unroll
    for (int mf = 0; mf < 4; ++mf) {
#pragma unroll
      for (int r = 0; r < 4; ++r) {
        const int m = m0 + mf * 16 + quad * 4 + r;
        out[(size_t)m * G4 + j] = acc[mf][nf][r] + bias;
      }
    }
  }
}

// ---------------------------------------------------------------------------
// Kernel C: fused LSTM + softmax + CRF, wave-specialized, ONE barrier/step.
// 768 threads: waves 0-7 LSTM (R10/R11-verified MFMA matvec + DPP cell);
// waves 8-11 CRF, lane owns (column j = cl>>1, K-half kh = cl&1) -> et is
// 32 VGPRs (R10's et[64] caused the 84-VGPR clamp + 1.1MB spill; fixed).
// amdgpu_waves_per_eu(3,3): 12 waves = 3/SIMD -> RA budget ~170 VGPR.
// Pipeline (R10-verified indexing, absmax=0): phase(s): LSTM h(s)->h(s+1)
// [ring 4]; CRF finalizes step s-1 (p from h32[s&3]=h_out(s-1); S(s-1) from
// E16[(s&1)^1]=E(s-2)).  Per-32-col wave normalizers M[4]; S reconstructed
// as C+log(sum_g e^{M_g-C} S_g) — R10's 2-group formula extended to 4;
// K-half partials combined with one quad_perm DPP swap (lanes 2j<->2j+1).
// ---------------------------------------------------------------------------
__global__ __launch_bounds__(768, 1)
__attribute__((amdgpu_waves_per_eu(3, 3)))
void lstm_crf(
    const float* __restrict__ precomp, const float* __restrict__ Whh,
    const float* __restrict__ trans, const int* __restrict__ labels,
    float* __restrict__ out_b) {
  const int b = blockIdx.x, t = threadIdx.x;
  const int w = t >> 6, l = t & 63, q = l >> 4, l15 = l & 15;
  const int tf_a = l15 & 3;        // tile this lane activates (LSTM)
  const int gg = l15 >> 2;         // gate this lane activates (LSTM)
  const bool isL = (w < 8);
  const int cl = t - 512;          // CRF lane 0..255 (when !isL)
  const int cw = cl >> 6;          // CRF wave 0..3
  const int lcl = cl & 63;         // lane within CRF wave
  const int j = cl >> 1;           // CRF column 0..127
  const int kh = cl & 1;           // K-half 0/1

  __shared__ __align__(16) _Float16 h16[4][HH];  // ring: matvec operand
  __shared__ __align__(16) float h32[4][HH];     // ring: softmax operand
  __shared__ __align__(16) _Float16 E16[2][HH];
  __shared__ float Mld[2][4];
  __shared__ float fin[12];
  __shared__ int lab[TT];

  // --- per-role one-time loads ---------------------------------------------
  f16x8 wfr[4][4];                 // LSTM: W_hh A-fragments
  f32x4 pc_cur[4], pc_nxt[4];      // LSTM: precomp prefetch
  const float* pcb = nullptr;
  float c = 0.f;                   // LSTM cell state (gg==0 lanes)
  half2_t et[32];                  // CRF: exp(trans[64kh+2a(+1)][j])
  float tr0 = 0.f, tr127 = 0.f, pre = 0.f, emit = 0.f;

  if (isL) {
#pragma unroll
    for (int tf = 0; tf < 4; ++tf) {
      const int rowp = 16 * (4 * w + tf) + l15;   // unit-major row index
      const int u = rowp >> 2, g = rowp & 3;
      const float* src = Whh + (size_t)(g * HH + u) * HH;
#pragma unroll
      for (int kt = 0; kt < 4; ++kt) {
        const float* s8 = src + kt * 32 + q * 8;
        float4 v0 = *(const float4*)s8;
        float4 v1 = *(const float4*)(s8 + 4);
        f16x8 h8;
        h8[0] = (_Float16)v0.x; h8[1] = (_Float16)v0.y;
        h8[2] = (_Float16)v0.z; h8[3] = (_Float16)v0.w;
        h8[4] = (_Float16)v1.x; h8[5] = (_Float16)v1.y;
        h8[6] = (_Float16)v1.z; h8[7] = (_Float16)v1.w;
        wfr[tf][kt] = h8;
      }
    }
    pcb = precomp + (size_t)b * TT * G4 + 64 * w + 4 * q;
#pragma unroll
    for (int tf = 0; tf < 4; ++tf) pc_cur[tf] = *(const f32x4*)(pcb + 16 * tf);
  } else {
#pragma unroll
    for (int a = 0; a < 32; ++a) {
      const int i0 = 64 * kh + 2 * a;
      float e0 = __expf(trans[i0 * HH + j]);
      float e1 = __expf(trans[(i0 + 1) * HH + j]);
      half2_t h2; h2[0] = (_Float16)e0; h2[1] = (_Float16)e1;
      et[a] = h2;
    }
    tr0 = trans[j];
    tr127 = trans[127 * HH + j];
  }
  if (t < TT) lab[t] = labels[b * TT + t];
  if (t < HH) { h16[0][t] = (_Float16)0.f; h32[0][t] = 0.f; }
  __syncthreads();

#pragma unroll 1
  for (int s = 0; s <= TT; ++s) {
    if (isL) {
      if (s < TT) {
        const int sn = (s < TT - 1) ? s + 1 : s;
#pragma unroll
        for (int tf = 0; tf < 4; ++tf)
          pc_nxt[tf] = *(const f32x4*)(pcb + (size_t)sn * G4 + 16 * tf);
        const int rs = s & 3;
        const f16x8 hb0 = *(const f16x8*)&h16[rs][q * 8];
        const f16x8 hb1 = *(const f16x8*)&h16[rs][32 + q * 8];
        const f16x8 hb2 = *(const f16x8*)&h16[rs][64 + q * 8];
        const f16x8 hb3 = *(const f16x8*)&h16[rs][96 + q * 8];
        f32x4 a0 = pc_cur[0], a1 = pc_cur[1], a2 = pc_cur[2], a3 = pc_cur[3];
        a0 = __builtin_amdgcn_mfma_f32_16x16x32_f16(wfr[0][0], hb0, a0, 0, 0, 0);
        a1 = __builtin_amdgcn_mfma_f32_16x16x32_f16(wfr[1][0], hb0, a1, 0, 0, 0);
        a2 = __builtin_amdgcn_mfma_f32_16x16x32_f16(wfr[2][0], hb0, a2, 0, 0, 0);
        a3 = __builtin_amdgcn_mfma_f32_16x16x32_f16(wfr[3][0], hb0, a3, 0, 0, 0);
        a0 = __builtin_amdgcn_mfma_f32_16x16x32_f16(wfr[0][1], hb1, a0, 0, 0, 0);
        a1 = __builtin_amdgcn_mfma_f32_16x16x32_f16(wfr[1][1], hb1, a1, 0, 0, 0);
        a2 = __builtin_amdgcn_mfma_f32_16x16x32_f16(wfr[2][1], hb1, a2, 0, 0, 0);
        a3 = __builtin_amdgcn_mfma_f32_16x16x32_f16(wfr[3][1], hb1, a3, 0, 0, 0);
        a0 = __builtin_amdgcn_mfma_f32_16x16x32_f16(wfr[0][2], hb2, a0, 0, 0, 0);
        a1 = __builtin_amdgcn_mfma_f32_16x16x32_f16(wfr[1][2], hb2, a1, 0, 0, 0);
        a2 = __builtin_amdgcn_mfma_f32_16x16x32_f16(wfr[2][2], hb2, a2, 0, 0, 0);
        a3 = __builtin_amdgcn_mfma_f32_16x16x32_f16(wfr[3][2], hb2, a3, 0, 0, 0);
        a0 = __builtin_amdgcn_mfma_f32_16x16x32_f16(wfr[0][3], hb3, a0, 0, 0, 0);
        a1 = __builtin_amdgcn_mfma_f32_16x16x32_f16(wfr[1][3], hb3, a1, 0, 0, 0);
        a2 = __builtin_amdgcn_mfma_f32_16x16x32_f16(wfr[2][3], hb3, a2, 0, 0, 0);
        a3 = __builtin_amdgcn_mfma_f32_16x16x32_f16(wfr[3][3], hb3, a3, 0, 0, 0);
        // one activation per lane (verified layout)
        const f32x4 asel = (tf_a == 0) ? a0 : (tf_a == 1) ? a1 : (tf_a == 2) ? a2 : a3;
        const float gv = (gg == 0) ? asel[0] : (gg == 1) ? asel[1]
                       : (gg == 2) ? asel[2] : asel[3];
        const bool isg = (gg == 2);               // gate 2 = g -> tanh
        const float yy = isg ? (-2.f * fabsf(gv)) : (-gv);
        const float exv = __expf(yy);
        const float num = isg ? (1.f - exv) : 1.f;
        float av = num * rcp_(1.f + exv);
        av = isg ? copysignf(av, gv) : av;
        // in-wave gather (R10-verified): gates of unit at l15 = tf + 4*gate
        float Fv, Gv, Ov;
        DPP_SHL(Fv, av, 4);   // gate 1 (f)
        DPP_SHL(Gv, av, 8);   // gate 2 (g, tanh'd)
        DPP_SHL(Ov, av, 12);  // gate 3 (o)
        c = Fv * c + av * Gv;               // valid on gg==0 lanes
        const float hv = Ov * tanh_(c);
        if (gg == 0) {
          const int ua = 16 * w + 4 * l15 + q;  // l15 == tf here
          h16[(s + 1) & 3][ua] = (_Float16)hv;
          h32[(s + 1) & 3][ua] = hv;
        }
#pragma unroll
        for (int tf = 0; tf < 4; ++tf) pc_cur[tf] = pc_nxt[tf];
      }
    } else if (s >= 1) {
      // --- CRF finalize step s-1: h_out(s-1) = h(s) in ring slot s&3 -------
      const int rs = s & 3;
      const float2 hp = *(const float2*)&h32[rs][2 * lcl];
      const float denom = wave_sum64_bcast(__expf(hp.x) + __expf(hp.y));
      const float hj = h32[rs][j];
      const float p = __expf(hj) * rcp_(denom);
      if (s == 1) {
        pre = p + tr0;
      } else {
        const int rp = (s & 1) ^ 1;   // E/M written last phase
        float Sa = 0.f, Sb = 0.f;     // source groups 2kh, 2kh+1
        const float4* ev = (const float4*)&E16[rp][64 * kh];
#pragma unroll
        for (int ec = 0; ec < 4; ++ec) {
          const float4 eb = ev[ec];
          Sa = fdot2f(et[4 * ec + 0], BC(eb.x), Sa);
          Sa = fdot2f(et[4 * ec + 1], BC(eb.y), Sa);
          Sa = fdot2f(et[4 * ec + 2], BC(eb.z), Sa);
          Sa = fdot2f(et[4 * ec + 3], BC(eb.w), Sa);
        }
#pragma unroll
        for (int ec = 4; ec < 8; ++ec) {
          const float4 eb = ev[ec];
          Sb = fdot2f(et[4 * ec + 0], BC(eb.x), Sb);
          Sb = fdot2f(et[4 * ec + 1], BC(eb.y), Sb);
          Sb = fdot2f(et[4 * ec + 2], BC(eb.z), Sb);
          Sb = fdot2f(et[4 * ec + 3], BC(eb.w), Sb);
        }
        const float M0 = Mld[rp][0], M1 = Mld[rp][1];
        const float M2 = Mld[rp][2], M3 = Mld[rp][3];
        const float Cc = fmaxf(fmaxf(M0, M1), fmaxf(M2, M3));
        const float Ma = (kh == 0) ? M0 : M2;
        const float Mb = (kh == 0) ? M1 : M3;
        float Sp = __expf(Ma - Cc) * Sa + __expf(Mb - Cc) * Sb;
        float Spo;
        DPP_QSWAP(Spo, Sp);           // partner K-half (lane 2j <-> 2j+1)
        pre = p + Cc + __logf(Sp + Spo);
      }
      if (kh == 0 && j == lab[s - 1]) emit += p;
      const float Mw = readlane_f(pre, 0);   // wave's col 32cw normalizer
      if (kh == 0) E16[s & 1][j] = (_Float16)__expf(pre - Mw);
      if (lcl == 0) Mld[s & 1][cw] = Mw;
    }
    BAR();
  }
  // --- epilogue: Ps = LSE_j(pre + trans[127][j]); out_b = Ps - emit --------
  if (!isL) {
    float v = (kh == 0) ? (pre + tr127) : -3.0e38f;
#pragma unroll
    for (int s2 = 1; s2 <= 32; s2 <<= 1) v = fmaxf(v, __shfl_xor(v, s2));
    if (lcl == 0) fin[cw] = v;
  }
  __syncthreads();
  if (!isL) {
    const float C4 = fmaxf(fmaxf(fin[0], fin[1]), fmaxf(fin[2], fin[3]));
    float ex = (kh == 0) ? __expf(pre + tr127 - C4) : 0.f;
    float em = emit;  // nonzero only on kh==0 lanes
#pragma unroll
    for (int s2 = 1; s2 <= 32; s2 <<= 1) {
      ex += __shfl_xor(ex, s2);
      em += __shfl_xor(em, s2);
    }
    if (lcl == 0) { fin[4 + cw] = ex; fin[8 + cw] = em; }
  }
  __syncthreads();
  if (t == 0) {
    const float C4 = fmaxf(fmaxf(fin[0], fin[1]), fmaxf(fin[2], fin[3]));
    out_b[b] = C4 + __logf(fin[4] + fin[5] + fin[6] + fin[7]) -
               (fin[8] + fin[9] + fin[10] + fin[11]);
  }
}

// ---------------------------------------------------------------------------
// Kernel D: total = sum_b out_b[b] - sum_{b,t<511} trans[l_t][l_{t+1}]
// ---------------------------------------------------------------------------
__global__ __launch_bounds__(512) void finalize_kernel(
    const float* __restrict__ trans, const int* __restrict__ labels,
    const float* __restrict__ out_b, float* __restrict__ d_out) {
  const int t = threadIdx.x;
  float a = 0.f;
  if (t < TT - 1) {
    for (int b = 0; b < BB; ++b) {
      const int l0 = labels[b * TT + t];
      const int l1 = labels[b * TT + t + 1];
      a += trans[l0 * HH + l1];
    }
  }
  float x = ((t < BB) ? out_b[t] : 0.f) - a;
  __shared__ float red[8];
#pragma unroll
  for (int s = 32; s >= 1; s >>= 1) x += __shfl_xor(x, s);
  if ((t & 63) == 0) red[t >> 6] = x;
  __syncthreads();
  if (t == 0) {
    float s = 0.f;
#pragma unroll
    for (int i = 0; i < 8; ++i) s += red[i];
    d_out[0] = s;
  }
}

// ---------------------------------------------------------------------------
extern "C" void kernel_launch(void* const* d_in, const int* in_sizes, int n_in,
                              void* d_out, int out_size, void* d_ws, size_t ws_size,
                              hipStream_t stream) {
  const float* inputs = (const float*)d_in[0];      // (64,512,256) f32
  const int* labels = (const int*)d_in[1];          // (64,512) i32
  const float* W_ih = (const float*)d_in[2];        // (512,256) f32
  const float* W_hh = (const float*)d_in[3];        // (512,128) f32
  const float* b_ih = (const float*)d_in[4];        // (512,) f32
  const float* b_hh = (const float*)d_in[5];        // (512,) f32
  const float* transition = (const float*)d_in[6];  // (128,128) f32

  char* ws = (char*)d_ws;
  float* precomp = (float*)ws;                           // 64 MiB
  float* trans = (float*)(ws + 67108864);                // 64 KiB
  _Float16* W16 = (_Float16*)(ws + 67108864 + 65536);    // 256 KiB
  float* out_b = (float*)(ws + 67108864 + 65536 + 262144);

  prep_kernel<<<256, 128, 0, stream>>>(transition, W_ih, trans, W16);
  gemm_in<<<dim3(512, 2), 256, 0, stream>>>(inputs, W16, b_ih, b_hh, precomp);
  lstm_crf<<<64, 768, 0, stream>>>(precomp, W_hh, trans, labels, out_b);
  finalize_kernel<<<1, 512, 0, stream>>>(trans, labels, out_b, (float*)d_out);
}